// Round 1
// baseline (125.519 us; speedup 1.0000x reference)
//
#include <hip/hip_runtime.h>

#define BB 4
#define CC 32
#define HH 512
#define WW 512

__global__ __launch_bounds__(256) void warp_bilinear_kernel(
    const float* __restrict__ src,
    const float* __restrict__ flow,
    float* __restrict__ out)
{
    const int HW = HH * WW;
    int idx = blockIdx.x * blockDim.x + threadIdx.x;   // pixel index in [0, B*H*W)
    if (idx >= BB * HW) return;

    int b = idx / HW;
    int p = idx - b * HW;
    int h = p / WW;
    int w = p - h * WW;

    // flow channel 0 = y offset, channel 1 = x offset
    float fy = flow[(b * 2 + 0) * HW + p];
    float fx = flow[(b * 2 + 1) * HW + p];

    float y = fminf(fmaxf((float)h + fy, 0.0f), (float)(HH - 1));
    float x = fminf(fmaxf((float)w + fx, 0.0f), (float)(WW - 1));

    float y0f = floorf(y);
    float x0f = floorf(x);
    float wy = y - y0f;
    float wx = x - x0f;

    int y0 = (int)y0f;
    int x0 = (int)x0f;
    int y1 = min(y0 + 1, HH - 1);
    int x1 = min(x0 + 1, WW - 1);

    float w00 = (1.0f - wy) * (1.0f - wx);
    float w01 = (1.0f - wy) * wx;
    float w10 = wy * (1.0f - wx);
    float w11 = wy * wx;

    int i00 = y0 * WW + x0;
    int i01 = y0 * WW + x1;
    int i10 = y1 * WW + x0;
    int i11 = y1 * WW + x1;

    const float* sb = src + (size_t)b * CC * HW;
    float*       ob = out + (size_t)b * CC * HW;

    #pragma unroll
    for (int c = 0; c < CC; ++c) {
        int off = c * HW;
        float v = sb[off + i00] * w00
                + sb[off + i01] * w01
                + sb[off + i10] * w10
                + sb[off + i11] * w11;
        ob[off + p] = v;
    }
}

extern "C" void kernel_launch(void* const* d_in, const int* in_sizes, int n_in,
                              void* d_out, int out_size, void* d_ws, size_t ws_size,
                              hipStream_t stream) {
    const float* src  = (const float*)d_in[0];
    const float* flow = (const float*)d_in[1];
    float* out = (float*)d_out;

    const int npix = BB * HH * WW;             // 1,048,576
    const int block = 256;
    const int grid = (npix + block - 1) / block;
    warp_bilinear_kernel<<<grid, block, 0, stream>>>(src, flow, out);
}

// Round 2
// 95.879 us; speedup vs baseline: 1.3091x; 1.3091x over previous
//
#include <hip/hip_runtime.h>

#define BB 4
#define CC 32
#define HH 512
#define WW 512

__global__ __launch_bounds__(256) void warp_bilinear_kernel(
    const float* __restrict__ src,
    const float* __restrict__ flow,
    float* __restrict__ out)
{
    const int HW = HH * WW;

    // Bijective XCD swizzle: HW assigns block i to XCD i%8 (round-robin).
    // Remap so each XCD's blocks cover a contiguous pixel range -> tap-halo
    // rows shared by vertical neighbors stay in the same XCD's L2.
    // gridDim.x == 4096, divisible by 8 -> simple form is bijective.
    int nper = gridDim.x >> 3;
    int bid = (blockIdx.x & 7) * nper + (blockIdx.x >> 3);

    int idx = bid * blockDim.x + threadIdx.x;   // pixel index in [0, B*H*W)

    int b = idx >> 18;            // HW = 2^18
    int p = idx & (HW - 1);
    int h = p >> 9;               // WW = 2^9
    int w = p & (WW - 1);

    // flow channel 0 = y offset, channel 1 = x offset (read once, no reuse -> nt)
    float fy = __builtin_nontemporal_load(flow + (b * 2 + 0) * HW + p);
    float fx = __builtin_nontemporal_load(flow + (b * 2 + 1) * HW + p);

    float y = fminf(fmaxf((float)h + fy, 0.0f), (float)(HH - 1));
    float x = fminf(fmaxf((float)w + fx, 0.0f), (float)(WW - 1));

    float y0f = floorf(y);
    float x0f = floorf(x);
    float wy = y - y0f;
    float wx = x - x0f;

    int y0 = (int)y0f;
    int x0 = (int)x0f;
    int y1 = min(y0 + 1, HH - 1);
    int x1 = min(x0 + 1, WW - 1);

    float w00 = (1.0f - wy) * (1.0f - wx);
    float w01 = (1.0f - wy) * wx;
    float w10 = wy * (1.0f - wx);
    float w11 = wy * wx;

    int i00 = y0 * WW + x0;
    int i01 = y0 * WW + x1;
    int i10 = y1 * WW + x0;
    int i11 = y1 * WW + x1;

    const float* sb = src + (size_t)b * CC * HW;
    float*       ob = out + (size_t)b * CC * HW;

    // Batch 8 channels: 32 gathers in flight before any waitcnt -> hide L2/L3
    // latency. Stores are nontemporal so the write stream doesn't evict src
    // from L2/L3 (src + out + flow = 264 MiB > 256 MiB L3 otherwise).
    #pragma unroll
    for (int c0 = 0; c0 < CC; c0 += 8) {
        float v00[8], v01[8], v10[8], v11[8];
        #pragma unroll
        for (int k = 0; k < 8; ++k) {
            const float* s = sb + (c0 + k) * HW;
            v00[k] = s[i00];
            v01[k] = s[i01];
            v10[k] = s[i10];
            v11[k] = s[i11];
        }
        #pragma unroll
        for (int k = 0; k < 8; ++k) {
            float v = v00[k] * w00 + v01[k] * w01 + v10[k] * w10 + v11[k] * w11;
            __builtin_nontemporal_store(v, ob + (c0 + k) * HW + p);
        }
    }
}

extern "C" void kernel_launch(void* const* d_in, const int* in_sizes, int n_in,
                              void* d_out, int out_size, void* d_ws, size_t ws_size,
                              hipStream_t stream) {
    const float* src  = (const float*)d_in[0];
    const float* flow = (const float*)d_in[1];
    float* out = (float*)d_out;

    const int npix = BB * HH * WW;             // 1,048,576
    const int block = 256;
    const int grid = npix / block;             // 4096, divisible by 8
    warp_bilinear_kernel<<<grid, block, 0, stream>>>(src, flow, out);
}

// Round 3
// 80.157 us; speedup vs baseline: 1.5659x; 1.1961x over previous
//
#include <hip/hip_runtime.h>

#define BB 4
#define CC 32
#define HH 512
#define WW 512

// 8-byte vector load with only 4-byte alignment guarantee (x0 may be odd).
typedef float f2v __attribute__((ext_vector_type(2), aligned(4)));

__global__ __launch_bounds__(256) void warp_bilinear_kernel(
    const float* __restrict__ src,
    const float* __restrict__ flow,
    float* __restrict__ out)
{
    const int HW = HH * WW;

    // Bijective XCD swizzle (gridDim.x == 4096, divisible by 8).
    int nper = gridDim.x >> 3;
    int bid = (blockIdx.x & 7) * nper + (blockIdx.x >> 3);

    int idx = bid * blockDim.x + threadIdx.x;   // pixel index in [0, B*H*W)

    int b = idx >> 18;            // HW = 2^18
    int p = idx & (HW - 1);
    int h = p >> 9;               // WW = 2^9
    int w = p & (WW - 1);

    // flow channel 0 = y offset, channel 1 = x offset (streamed once -> nt)
    float fy = __builtin_nontemporal_load(flow + (b * 2 + 0) * HW + p);
    float fx = __builtin_nontemporal_load(flow + (b * 2 + 1) * HW + p);

    float y = fminf(fmaxf((float)h + fy, 0.0f), (float)(HH - 1));
    float x = fminf(fmaxf((float)w + fx, 0.0f), (float)(WW - 1));

    // Border fold: x0 = min(floor(x), W-2) with wx = x - x0 gives results
    // identical to the reference's (floor, clamp-neighbor) formulation:
    // for x in [W-2, W-1) nothing changes; for x == W-1 exactly, wx == 1 so
    // the left tap gets weight exactly 0. Guarantees x1 == x0+1 always ->
    // each row-tap is ONE float2 load instead of two scalar gathers.
    int y0 = min((int)floorf(y), HH - 2);
    int x0 = min((int)floorf(x), WW - 2);
    float wy = y - (float)y0;
    float wx = x - (float)x0;

    float w00 = (1.0f - wy) * (1.0f - wx);
    float w01 = (1.0f - wy) * wx;
    float w10 = wy * (1.0f - wx);
    float w11 = wy * wx;

    int i0 = y0 * WW + x0;        // top-left  (covers x0, x0+1)
    int i1 = i0 + WW;             // bottom-left

    const float* sb = src + (size_t)b * CC * HW;
    float*       ob = out + (size_t)b * CC * HW;

    // 8 channels per batch: 16 dwordx2 gathers in flight -> hide L2/L3 latency.
    #pragma unroll
    for (int c0 = 0; c0 < CC; c0 += 8) {
        f2v t[8], bt[8];
        #pragma unroll
        for (int k = 0; k < 8; ++k) {
            const float* s = sb + (c0 + k) * HW;
            t[k]  = *(const f2v*)(s + i0);
            bt[k] = *(const f2v*)(s + i1);
        }
        #pragma unroll
        for (int k = 0; k < 8; ++k) {
            float v = t[k].x * w00 + t[k].y * w01
                    + bt[k].x * w10 + bt[k].y * w11;
            __builtin_nontemporal_store(v, ob + (c0 + k) * HW + p);
        }
    }
}

extern "C" void kernel_launch(void* const* d_in, const int* in_sizes, int n_in,
                              void* d_out, int out_size, void* d_ws, size_t ws_size,
                              hipStream_t stream) {
    const float* src  = (const float*)d_in[0];
    const float* flow = (const float*)d_in[1];
    float* out = (float*)d_out;

    const int npix = BB * HH * WW;             // 1,048,576
    const int block = 256;
    const int grid = npix / block;             // 4096, divisible by 8
    warp_bilinear_kernel<<<grid, block, 0, stream>>>(src, flow, out);
}